// Round 3
// baseline (861.750 us; speedup 1.0000x reference)
//
#include <hip/hip_runtime.h>

typedef unsigned short u16;
typedef __bf16 bf16x8 __attribute__((ext_vector_type(8)));
typedef u16   u16x8  __attribute__((ext_vector_type(8)));
typedef float f32x4  __attribute__((ext_vector_type(4)));

// packed row layout: per batch, modality rows at OFFS[m], total RPB rows/batch
#define RPB 5084
#define SL0 2048
#define SL1 1024
#define SL2 1500
#define SL3 512

// ---------- helpers ----------
__device__ __forceinline__ u16 f2bf(float f) {
  union { float f; unsigned u; } x; x.f = f;
  unsigned u = x.u;
  u += 0x7fffu + ((u >> 16) & 1u);   // RNE
  return (u16)(u >> 16);
}
__device__ __forceinline__ float bf2f(u16 h) {
  union { unsigned u; float f; } x; x.u = ((unsigned)h) << 16;
  return x.f;
}

// ---------- bf16 MFMA GEMM: C[Mr x N] = A[Mr x K] @ B[N x K]^T + bias0 + bias1 ----------
// A: fp32 (converted in staging) or bf16, selected by template. B: always fp32 weights.
// 128x128 tile, BK=32, 256 threads = 4 waves, each wave 64x64 (4x4 of 16x16x32 MFMA).
// Output rows optionally remapped (sl>0): gr -> (gr/sl)*obstride + obase + (gr%sl).
#define LDT 40   // padded LDS row stride (elems): 80B -> 2-way bank alias only (free, m136)

template<bool AF32>
__global__ __launch_bounds__(256) void gemm_bt(
    const void* __restrict__ Av, const float* __restrict__ Bw,
    const float* __restrict__ bias0, const float* __restrict__ bias1,
    void* __restrict__ Cout, int Mr, int N, int K,
    int out_bf16, int sl, int obase, int obstride)
{
  __shared__ u16 lA[128 * LDT];
  __shared__ u16 lB[128 * LDT];
  const int tid  = threadIdx.x;
  const int lane = tid & 63;
  const int wave = tid >> 6;
  const int wr   = (wave >> 1) * 64;
  const int wc   = (wave & 1) * 64;
  const int row0 = blockIdx.y * 128;
  const int col0 = blockIdx.x * 128;

  // staging: thread t handles 16 contiguous k of A-row (t>>1) and B-row (t>>1), half (t&1)
  const int ar = tid >> 1;
  const int ac = (tid & 1) * 16;
  int arow = row0 + ar; if (arow >= Mr) arow = Mr - 1;  // clamp: garbage only reaches masked C rows
  const float* gAf = (const float*)Av + (size_t)arow * K + ac;  // used if AF32
  const u16*   gAh = (const u16*)Av   + (size_t)arow * K + ac;  // used if !AF32
  const float* gBf = Bw + (size_t)(col0 + ar) * K + ac;

  f32x4 acc[4][4];
#pragma unroll
  for (int i = 0; i < 4; ++i)
#pragma unroll
    for (int j = 0; j < 4; ++j) acc[i][j] = f32x4{0.f, 0.f, 0.f, 0.f};

  const int fr = lane & 15;
  const int fk = (lane >> 4) * 8;

  for (int k0 = 0; k0 < K; k0 += 32) {
    u16x8 a0, a1, b0, b1;
    if (AF32) {
      f32x4 v0 = *(const f32x4*)(gAf + k0);
      f32x4 v1 = *(const f32x4*)(gAf + k0 + 4);
      f32x4 v2 = *(const f32x4*)(gAf + k0 + 8);
      f32x4 v3 = *(const f32x4*)(gAf + k0 + 12);
#pragma unroll
      for (int i = 0; i < 4; ++i) {
        a0[i] = f2bf(v0[i]); a0[i + 4] = f2bf(v1[i]);
        a1[i] = f2bf(v2[i]); a1[i + 4] = f2bf(v3[i]);
      }
    } else {
      a0 = *(const u16x8*)(gAh + k0);
      a1 = *(const u16x8*)(gAh + k0 + 8);
    }
    {
      f32x4 v0 = *(const f32x4*)(gBf + k0);
      f32x4 v1 = *(const f32x4*)(gBf + k0 + 4);
      f32x4 v2 = *(const f32x4*)(gBf + k0 + 8);
      f32x4 v3 = *(const f32x4*)(gBf + k0 + 12);
#pragma unroll
      for (int i = 0; i < 4; ++i) {
        b0[i] = f2bf(v0[i]); b0[i + 4] = f2bf(v1[i]);
        b1[i] = f2bf(v2[i]); b1[i + 4] = f2bf(v3[i]);
      }
    }
    __syncthreads();
    *(u16x8*)&lA[ar * LDT + ac]     = a0;
    *(u16x8*)&lA[ar * LDT + ac + 8] = a1;
    *(u16x8*)&lB[ar * LDT + ac]     = b0;
    *(u16x8*)&lB[ar * LDT + ac + 8] = b1;
    __syncthreads();

    bf16x8 af[4], bfr[4];
#pragma unroll
    for (int i = 0; i < 4; ++i)
      af[i] = *(const bf16x8*)&lA[(wr + i * 16 + fr) * LDT + fk];
#pragma unroll
    for (int j = 0; j < 4; ++j)
      bfr[j] = *(const bf16x8*)&lB[(wc + j * 16 + fr) * LDT + fk];
#pragma unroll
    for (int i = 0; i < 4; ++i)
#pragma unroll
      for (int j = 0; j < 4; ++j)
        acc[i][j] = __builtin_amdgcn_mfma_f32_16x16x32_bf16(af[i], bfr[j], acc[i][j], 0, 0, 0);
  }

  // epilogue: C/D layout col = lane&15, row = (lane>>4)*4 + reg  [m89/m91 verified]
  const int fc = lane & 15;
  const int rq = (lane >> 4) * 4;
#pragma unroll
  for (int i = 0; i < 4; ++i) {
#pragma unroll
    for (int j = 0; j < 4; ++j) {
      const int c = col0 + wc + j * 16 + fc;
      float badd = (bias0 ? bias0[c] : 0.f) + (bias1 ? bias1[c] : 0.f);
#pragma unroll
      for (int reg = 0; reg < 4; ++reg) {
        int gr = row0 + wr + i * 16 + rq + reg;
        if (gr < Mr) {
          int orow;
          if (sl > 0) { int bb = gr / sl; int ss = gr - bb * sl; orow = bb * obstride + obase + ss; }
          else orow = gr;
          float v = acc[i][j][reg] + badd;
          if (out_bf16) ((u16*)Cout)[(size_t)orow * N + c] = f2bf(v);
          else          ((float*)Cout)[(size_t)orow * N + c] = v;
        }
      }
    }
  }
}

// ---------- windowed attention over routed modalities + mean over m ----------
// one wave per (b,s,h). Q/K/V stored only for real (unpadded) rows; padded rows
// are exactly the bias vector (stacked pad = 0), synthesized from bq/bk/bv.
// ROUTES derivation: c = [0.0, 0.0, 0.5, 0.99609375]  (note (1/3)*3==1.0 and
// (2/3)*3==2.0 exactly in IEEE double -> d=1/d=2 then x=0 on first Cantor step)
// => stable argsort of |c_i - c_j| rows, first 3:
//    m=0:[0,1,2] m=1:[0,1,2] m=2:[2,3,0] m=3:[3,2,0]
__global__ __launch_bounds__(256) void attn_fuse(
    const u16* __restrict__ Q, const u16* __restrict__ K, const u16* __restrict__ V,
    u16* __restrict__ fused,
    const float* __restrict__ bq, const float* __restrict__ bk, const float* __restrict__ bv,
    const float* __restrict__ temp_ptr)
{
  const int ROUTE[4][3] = {{0,1,2},{0,1,2},{2,3,0},{3,2,0}};
  const int SLm[4]  = {SL0, SL1, SL2, SL3};
  const int OFFS[4] = {0, 2048, 3072, 4572};
  const int tid  = threadIdx.x;
  const int lane = tid & 63;
  const int u    = blockIdx.x * 4 + (tid >> 6);  // (b*S+s)*H + h
  const int h    = u & 15;
  const int bs   = u >> 4;          // b*S + s
  const int s    = bs & 2047;
  const int b    = bs >> 11;
  const float scale = 1.0f / (8.0f * fabsf(temp_ptr[0]));
  const int dbase = h * 64 + lane;

  float acc = 0.f;
#pragma unroll
  for (int m = 0; m < 4; ++m) {
    float qv = (s < SLm[m])
      ? bf2f(Q[((size_t)(b * RPB + OFFS[m] + s)) * 1024 + dbase])
      : bq[dbase];
    float sc[3];
#pragma unroll
    for (int w = 0; w < 3; ++w) {
      int r = ROUTE[m][w];
      float kv = (s < SLm[r])
        ? bf2f(K[((size_t)(b * RPB + OFFS[r] + s)) * 1024 + dbase])
        : bk[dbase];
      float d = qv * kv;
#pragma unroll
      for (int o = 32; o; o >>= 1) d += __shfl_xor(d, o, 64);
      sc[w] = d * scale;
    }
    float mx = fmaxf(sc[0], fmaxf(sc[1], sc[2]));
    float e0 = __expf(sc[0] - mx), e1 = __expf(sc[1] - mx), e2 = __expf(sc[2] - mx);
    float inv = 1.0f / (e0 + e1 + e2);
    float ws[3] = {e0 * inv, e1 * inv, e2 * inv};
#pragma unroll
    for (int w = 0; w < 3; ++w) {
      int r = ROUTE[m][w];
      float vv = (s < SLm[r])
        ? bf2f(V[((size_t)(b * RPB + OFFS[r] + s)) * 1024 + dbase])
        : bv[dbase];
      acc += ws[w] * vv;
    }
  }
  fused[(size_t)bs * 1024 + dbase] = f2bf(acc * 0.25f);
}

// ---------- host orchestration ----------
extern "C" void kernel_launch(void* const* d_in, const int* in_sizes, int n_in,
                              void* d_out, int out_size, void* d_ws, size_t ws_size,
                              hipStream_t stream) {
  const int B = 4, S = 2048, D = 1024;
  const int SL[4]   = {SL0, SL1, SL2, SL3};
  const int DIM[4]  = {768, 1024, 512, 2048};
  const int OFFS[4] = {0, 2048, 3072, 4572};

  const float* x[4]  = {(const float*)d_in[0], (const float*)d_in[3], (const float*)d_in[6], (const float*)d_in[9]};
  const float* Wm[4] = {(const float*)d_in[1], (const float*)d_in[4], (const float*)d_in[7], (const float*)d_in[10]};
  const float* bm[4] = {(const float*)d_in[2], (const float*)d_in[5], (const float*)d_in[8], (const float*)d_in[11]};
  const float* mod_emb = (const float*)d_in[12];
  const float* Wq = (const float*)d_in[13]; const float* bq = (const float*)d_in[14];
  const float* Wk = (const float*)d_in[15]; const float* bk = (const float*)d_in[16];
  const float* Wv = (const float*)d_in[17]; const float* bv = (const float*)d_in[18];
  const float* Wo = (const float*)d_in[19]; const float* bo = (const float*)d_in[20];
  const float* temp = (const float*)d_in[21];

  const int RROWS = B * RPB;                 // 20336 real rows
  const size_t bufBytes = ((size_t)RROWS * D * 2 + 255) / 256 * 256;
  if (ws_size < 4 * bufBytes) return;        // guard: clean failure instead of OOB crash

  char* p = (char*)d_ws;
  u16* stacked = (u16*)p;               p += bufBytes;
  u16* Qb      = (u16*)p;               p += bufBytes;
  u16* Kb      = (u16*)p;               p += bufBytes;
  u16* Vb      = (u16*)p;
  u16* fusedb  = stacked;               // stacked is dead after the V GEMM

  // projections into packed stacked (row remap), bf16 out; A and B staged from fp32
  for (int m = 0; m < 4; ++m) {
    int Mr = B * SL[m];
    dim3 grid(D / 128, (Mr + 127) / 128);
    gemm_bt<true><<<grid, 256, 0, stream>>>(x[m], Wm[m], bm[m], mod_emb + m * D,
                                            stacked, Mr, D, DIM[m], 1, SL[m], OFFS[m], RPB);
  }

  // Q/K/V GEMMs over the 20336 packed rows, bf16 out
  {
    dim3 grid(D / 128, (RROWS + 127) / 128);
    gemm_bt<false><<<grid, 256, 0, stream>>>(stacked, Wq, bq, nullptr, Qb, RROWS, D, D, 1, 0, 0, 0);
    gemm_bt<false><<<grid, 256, 0, stream>>>(stacked, Wk, bk, nullptr, Kb, RROWS, D, D, 1, 0, 0, 0);
    gemm_bt<false><<<grid, 256, 0, stream>>>(stacked, Wv, bv, nullptr, Vb, RROWS, D, D, 1, 0, 0, 0);
  }

  // attention over window + mean over modalities -> fused (bf16, full B*S rows)
  attn_fuse<<<(B * S * 16) / 4, 256, 0, stream>>>(Qb, Kb, Vb, fusedb, bq, bk, bv, temp);

  // output GEMM: (B*S) x D x D, fp32 out
  {
    dim3 grid(D / 128, (B * S) / 128);
    gemm_bt<false><<<grid, 256, 0, stream>>>(fusedb, Wo, bo, nullptr, d_out, B * S, D, D, 0, 0, 0, 0);
  }
}

// Round 4
// 649.973 us; speedup vs baseline: 1.3258x; 1.3258x over previous
//
#include <hip/hip_runtime.h>

typedef unsigned short u16;
typedef __bf16 bf16x8 __attribute__((ext_vector_type(8)));
typedef u16   u16x8  __attribute__((ext_vector_type(8)));
typedef float f32x4  __attribute__((ext_vector_type(4)));

// packed row layout: per batch, modality rows at OFFS[m], total RPB rows/batch
#define RPB 5084
#define SL0 2048
#define SL1 1024
#define SL2 1500
#define SL3 512

// ---------- helpers ----------
__device__ __forceinline__ u16 f2bf(float f) {
  union { float f; unsigned u; } x; x.f = f;
  unsigned u = x.u;
  u += 0x7fffu + ((u >> 16) & 1u);   // RNE
  return (u16)(u >> 16);
}
__device__ __forceinline__ float bf2f(u16 h) {
  union { unsigned u; float f; } x; x.u = ((unsigned)h) << 16;
  return x.f;
}
// async global->LDS, 16B per lane; dest = wave-uniform base + lane*16
__device__ __forceinline__ void gll16(const u16* g, u16* l) {
  __builtin_amdgcn_global_load_lds(
      (const __attribute__((address_space(1))) void*)g,
      (__attribute__((address_space(3))) void*)l, 16, 0, 0);
}

// ---------- fp32 -> bf16 conversion (weights) ----------
__global__ __launch_bounds__(256) void cvt_f2bf(const float* __restrict__ in,
                                                u16* __restrict__ out, int n) {
  int i = (blockIdx.x * 256 + threadIdx.x) * 4;
  if (i + 4 <= n) {
    f32x4 v = *(const f32x4*)(in + i);
    u16 o0 = f2bf(v[0]), o1 = f2bf(v[1]), o2 = f2bf(v[2]), o3 = f2bf(v[3]);
    u16* p = out + i; p[0] = o0; p[1] = o1; p[2] = o2; p[3] = o3;
  } else {
    for (; i < n; ++i) out[i] = f2bf(in[i]);
  }
}

// ---------- m97-style bf16 GEMM via global_load_lds ----------
// C[gr][blockIdx.x*128 + c] = A[gr][:] . Bw[colL + c][:]  + bias[colL+c]
// Bw/bias selected per 8-colblock group (QKV fusion: grid.x=24 -> Wq|Wk|Wv).
// 128x128 tile, BK=32, unpadded LDS [row][32] (m97 structure, 874 TF verified shape).
template<int STORE_F32>
__global__ __launch_bounds__(256) void gemm_lds(
    const u16* __restrict__ A,
    const u16* __restrict__ B0, const u16* __restrict__ B1, const u16* __restrict__ B2,
    const float* __restrict__ c0, const float* __restrict__ c1, const float* __restrict__ c2,
    void* __restrict__ Cout, int Mr, int K, int ldc)
{
  __shared__ u16 lA[128 * 32];
  __shared__ u16 lB[128 * 32];
  const int tid  = threadIdx.x;
  const int lane = tid & 63;
  const int wave = tid >> 6;
  const int wr   = (wave >> 1) * 64;
  const int wc   = (wave & 1) * 64;
  const int row0 = blockIdx.y * 128;

  const int wsel = blockIdx.x >> 3;          // which weight matrix
  const int colL = (blockIdx.x & 7) * 128;   // col offset within that W
  const u16*   Bw   = (wsel == 0) ? B0 : (wsel == 1) ? B1 : B2;
  const float* bias = (wsel == 0) ? c0 : (wsel == 1) ? c1 : c2;

  // staging map: wave handles rows wave*32 .. +31 (two 16-row instrs);
  // lane l -> row += l>>2, k-chunk (l&3)*8   (LDS dest = base + l*16, [row][32] layout)
  const int sr  = wave * 32 + (lane >> 2);
  const int sc  = (lane & 3) * 8;
  int ra0 = row0 + sr;      if (ra0 >= Mr) ra0 = Mr - 1;
  int ra1 = row0 + sr + 16; if (ra1 >= Mr) ra1 = Mr - 1;
  const u16* pA0 = A + (size_t)ra0 * K + sc;
  const u16* pA1 = A + (size_t)ra1 * K + sc;
  const u16* pB0 = Bw + (size_t)(colL + sr) * K + sc;
  const u16* pB1 = pB0 + (size_t)16 * K;
  u16* dA0 = &lA[(wave * 32) * 32];
  u16* dA1 = &lA[(wave * 32 + 16) * 32];
  u16* dB0 = &lB[(wave * 32) * 32];
  u16* dB1 = &lB[(wave * 32 + 16) * 32];

  f32x4 acc[4][4];
#pragma unroll
  for (int i = 0; i < 4; ++i)
#pragma unroll
    for (int j = 0; j < 4; ++j) acc[i][j] = f32x4{0.f, 0.f, 0.f, 0.f};

  const int fr = lane & 15;
  const int fk = (lane >> 4) * 8;

  for (int k0 = 0; k0 < K; k0 += 32) {
    __syncthreads();                       // prev-iter LDS reads done (compiler drains lgkm)
    gll16(pA0 + k0, dA0);
    gll16(pA1 + k0, dA1);
    gll16(pB0 + k0, dB0);
    gll16(pB1 + k0, dB1);
    __syncthreads();                       // vmcnt(0) drain: tile landed

    bf16x8 af[4], bfr[4];
#pragma unroll
    for (int i = 0; i < 4; ++i)
      af[i] = *(const bf16x8*)&lA[(wr + i * 16 + fr) * 32 + fk];
#pragma unroll
    for (int j = 0; j < 4; ++j)
      bfr[j] = *(const bf16x8*)&lB[(wc + j * 16 + fr) * 32 + fk];
#pragma unroll
    for (int i = 0; i < 4; ++i)
#pragma unroll
      for (int j = 0; j < 4; ++j)
        acc[i][j] = __builtin_amdgcn_mfma_f32_16x16x32_bf16(af[i], bfr[j], acc[i][j], 0, 0, 0);
  }

  // epilogue: C/D layout col = lane&15, row = (lane>>4)*4 + reg  [m89/m91]
  const int fc = lane & 15;
  const int rq = (lane >> 4) * 4;
#pragma unroll
  for (int i = 0; i < 4; ++i) {
#pragma unroll
    for (int j = 0; j < 4; ++j) {
      const int cl = wc + j * 16 + fc;               // col within tile
      const float badd = bias[colL + cl];
      const int gc = blockIdx.x * 128 + cl;          // col in output buffer
#pragma unroll
      for (int reg = 0; reg < 4; ++reg) {
        int gr = row0 + wr + i * 16 + rq + reg;
        if (gr < Mr) {
          float v = acc[i][j][reg] + badd;
          if (STORE_F32) ((float*)Cout)[(size_t)gr * ldc + gc] = v;
          else           ((u16*)Cout)[(size_t)gr * ldc + gc] = f2bf(v);
        }
      }
    }
  }
}

// ---------- projection GEMM (A fp32, staged+converted; padded LDS) ----------
#define LDT 40
__global__ __launch_bounds__(256) void gemm_proj(
    const float* __restrict__ Af, const float* __restrict__ Bw,
    const float* __restrict__ bias0, const float* __restrict__ bias1,
    u16* __restrict__ Cout, int Mr, int N, int K,
    int sl, int obase, int obstride)
{
  __shared__ u16 lA[128 * LDT];
  __shared__ u16 lB[128 * LDT];
  const int tid  = threadIdx.x;
  const int lane = tid & 63;
  const int wave = tid >> 6;
  const int wr   = (wave >> 1) * 64;
  const int wc   = (wave & 1) * 64;
  const int row0 = blockIdx.y * 128;
  const int col0 = blockIdx.x * 128;

  const int ar = tid >> 1;
  const int ac = (tid & 1) * 16;
  int arow = row0 + ar; if (arow >= Mr) arow = Mr - 1;
  const float* gAf = Af + (size_t)arow * K + ac;
  const float* gBf = Bw + (size_t)(col0 + ar) * K + ac;

  f32x4 acc[4][4];
#pragma unroll
  for (int i = 0; i < 4; ++i)
#pragma unroll
    for (int j = 0; j < 4; ++j) acc[i][j] = f32x4{0.f, 0.f, 0.f, 0.f};

  const int fr = lane & 15;
  const int fk = (lane >> 4) * 8;

  for (int k0 = 0; k0 < K; k0 += 32) {
    u16x8 a0, a1, b0, b1;
    {
      f32x4 v0 = *(const f32x4*)(gAf + k0);
      f32x4 v1 = *(const f32x4*)(gAf + k0 + 4);
      f32x4 v2 = *(const f32x4*)(gAf + k0 + 8);
      f32x4 v3 = *(const f32x4*)(gAf + k0 + 12);
#pragma unroll
      for (int i = 0; i < 4; ++i) {
        a0[i] = f2bf(v0[i]); a0[i + 4] = f2bf(v1[i]);
        a1[i] = f2bf(v2[i]); a1[i + 4] = f2bf(v3[i]);
      }
    }
    {
      f32x4 v0 = *(const f32x4*)(gBf + k0);
      f32x4 v1 = *(const f32x4*)(gBf + k0 + 4);
      f32x4 v2 = *(const f32x4*)(gBf + k0 + 8);
      f32x4 v3 = *(const f32x4*)(gBf + k0 + 12);
#pragma unroll
      for (int i = 0; i < 4; ++i) {
        b0[i] = f2bf(v0[i]); b0[i + 4] = f2bf(v1[i]);
        b1[i] = f2bf(v2[i]); b1[i + 4] = f2bf(v3[i]);
      }
    }
    __syncthreads();
    *(u16x8*)&lA[ar * LDT + ac]     = a0;
    *(u16x8*)&lA[ar * LDT + ac + 8] = a1;
    *(u16x8*)&lB[ar * LDT + ac]     = b0;
    *(u16x8*)&lB[ar * LDT + ac + 8] = b1;
    __syncthreads();

    bf16x8 af[4], bfr[4];
#pragma unroll
    for (int i = 0; i < 4; ++i)
      af[i] = *(const bf16x8*)&lA[(wr + i * 16 + fr) * LDT + fk];
#pragma unroll
    for (int j = 0; j < 4; ++j)
      bfr[j] = *(const bf16x8*)&lB[(wc + j * 16 + fr) * LDT + fk];
#pragma unroll
    for (int i = 0; i < 4; ++i)
#pragma unroll
      for (int j = 0; j < 4; ++j)
        acc[i][j] = __builtin_amdgcn_mfma_f32_16x16x32_bf16(af[i], bfr[j], acc[i][j], 0, 0, 0);
  }

  const int fc = lane & 15;
  const int rq = (lane >> 4) * 4;
#pragma unroll
  for (int i = 0; i < 4; ++i) {
#pragma unroll
    for (int j = 0; j < 4; ++j) {
      const int c = col0 + wc + j * 16 + fc;
      float badd = bias0[c] + bias1[c];
#pragma unroll
      for (int reg = 0; reg < 4; ++reg) {
        int gr = row0 + wr + i * 16 + rq + reg;
        if (gr < Mr) {
          int bb = gr / sl, ss = gr - bb * sl;
          Cout[(size_t)(bb * obstride + obase + ss) * N + c] = f2bf(acc[i][j][reg] + badd);
        }
      }
    }
  }
}

// ---------- windowed attention + mean over modalities ----------
// 8 lanes per head, 16B (bf16x8) per lane. Wave = 8 heads of one (b,s);
// block = 4 waves = 2 (b,s). Padded rows synthesized from biases (exact).
// ROUTES (IEEE-tie-corrected Cantor): m0:[0,1,2] m1:[0,1,2] m2:[2,3,0] m3:[3,2,0]
__global__ __launch_bounds__(256) void attn_fuse(
    const u16* __restrict__ QKV,   // [RROWS][3072]: Q|K|V
    u16* __restrict__ fused,
    const float* __restrict__ bq, const float* __restrict__ bk, const float* __restrict__ bv,
    const float* __restrict__ temp_ptr)
{
  const int ROUTE[4][3] = {{0,1,2},{0,1,2},{2,3,0},{3,2,0}};
  const int SLm[4]  = {SL0, SL1, SL2, SL3};
  const int OFFS[4] = {0, 2048, 3072, 4572};
  const int tid  = threadIdx.x;
  const int lane = tid & 63;
  const int wave = tid >> 6;
  const int bs   = blockIdx.x * 2 + (wave >> 1);
  const int s    = bs & 2047;
  const int b    = bs >> 11;
  const int h    = (wave & 1) * 8 + (lane >> 3);
  const int sub  = lane & 7;
  const int dbase = h * 64 + sub * 8;
  const float scale = 1.0f / (8.0f * fabsf(temp_ptr[0]));

  float acc[8];
#pragma unroll
  for (int i = 0; i < 8; ++i) acc[i] = 0.f;

#pragma unroll
  for (int m = 0; m < 4; ++m) {
    float qf[8];
    if (s < SLm[m]) {
      u16x8 q8 = *(const u16x8*)(QKV + ((size_t)(b * RPB + OFFS[m] + s)) * 3072 + dbase);
#pragma unroll
      for (int i = 0; i < 8; ++i) qf[i] = bf2f(q8[i]);
    } else {
#pragma unroll
      for (int i = 0; i < 8; ++i) qf[i] = bq[dbase + i];
    }
    float sc[3];
#pragma unroll
    for (int w = 0; w < 3; ++w) {
      const int r = ROUTE[m][w];
      float d = 0.f;
      if (s < SLm[r]) {
        u16x8 k8 = *(const u16x8*)(QKV + ((size_t)(b * RPB + OFFS[r] + s)) * 3072 + 1024 + dbase);
#pragma unroll
        for (int i = 0; i < 8; ++i) d += qf[i] * bf2f(k8[i]);
      } else {
#pragma unroll
        for (int i = 0; i < 8; ++i) d += qf[i] * bk[dbase + i];
      }
      d += __shfl_xor(d, 1, 64);
      d += __shfl_xor(d, 2, 64);
      d += __shfl_xor(d, 4, 64);
      sc[w] = d * scale;
    }
    float mx = fmaxf(sc[0], fmaxf(sc[1], sc[2]));
    float e0 = __expf(sc[0] - mx), e1 = __expf(sc[1] - mx), e2 = __expf(sc[2] - mx);
    float inv = 1.0f / (e0 + e1 + e2);
    float ws[3] = {e0 * inv, e1 * inv, e2 * inv};
#pragma unroll
    for (int w = 0; w < 3; ++w) {
      const int r = ROUTE[m][w];
      if (s < SLm[r]) {
        u16x8 v8 = *(const u16x8*)(QKV + ((size_t)(b * RPB + OFFS[r] + s)) * 3072 + 2048 + dbase);
#pragma unroll
        for (int i = 0; i < 8; ++i) acc[i] += ws[w] * bf2f(v8[i]);
      } else {
#pragma unroll
        for (int i = 0; i < 8; ++i) acc[i] += ws[w] * bv[dbase + i];
      }
    }
  }
  u16x8 o;
#pragma unroll
  for (int i = 0; i < 8; ++i) o[i] = f2bf(acc[i] * 0.25f);
  *(u16x8*)(fused + (size_t)bs * 1024 + dbase) = o;
}

// ---------- host orchestration ----------
extern "C" void kernel_launch(void* const* d_in, const int* in_sizes, int n_in,
                              void* d_out, int out_size, void* d_ws, size_t ws_size,
                              hipStream_t stream) {
  const int B = 4, S = 2048, D = 1024;
  const int SL[4]   = {SL0, SL1, SL2, SL3};
  const int DIM[4]  = {768, 1024, 512, 2048};
  const int OFFS[4] = {0, 2048, 3072, 4572};

  const float* x[4]  = {(const float*)d_in[0], (const float*)d_in[3], (const float*)d_in[6], (const float*)d_in[9]};
  const float* Wm[4] = {(const float*)d_in[1], (const float*)d_in[4], (const float*)d_in[7], (const float*)d_in[10]};
  const float* bm[4] = {(const float*)d_in[2], (const float*)d_in[5], (const float*)d_in[8], (const float*)d_in[11]};
  const float* mod_emb = (const float*)d_in[12];
  const float* Wq = (const float*)d_in[13]; const float* bq = (const float*)d_in[14];
  const float* Wk = (const float*)d_in[15]; const float* bk = (const float*)d_in[16];
  const float* Wv = (const float*)d_in[17]; const float* bv = (const float*)d_in[18];
  const float* Wo = (const float*)d_in[19]; const float* bo = (const float*)d_in[20];
  const float* temp = (const float*)d_in[21];

  const int RROWS = B * RPB;                 // 20336 real rows
  const size_t stackedB = ((size_t)RROWS * D * 2 + 255) / 256 * 256;
  const size_t qkvB     = ((size_t)RROWS * 3 * D * 2 + 255) / 256 * 256;
  const size_t wB       = ((size_t)D * D * 2 + 255) / 256 * 256;
  if (ws_size < stackedB + qkvB + 4 * wB) return;   // clean failure, not OOB crash

  char* p = (char*)d_ws;
  u16* stacked = (u16*)p;  p += stackedB;
  u16* qkv     = (u16*)p;  p += qkvB;
  u16* wqb     = (u16*)p;  p += wB;
  u16* wkb     = (u16*)p;  p += wB;
  u16* wvb     = (u16*)p;  p += wB;
  u16* wob     = (u16*)p;
  u16* fusedb  = stacked;  // stacked dead after QKV GEMM

  // convert QKV/O weights to bf16 (1M elems each)
  {
    int n = D * D, blocks = n / 1024;
    cvt_f2bf<<<blocks, 256, 0, stream>>>(Wq, wqb, n);
    cvt_f2bf<<<blocks, 256, 0, stream>>>(Wk, wkb, n);
    cvt_f2bf<<<blocks, 256, 0, stream>>>(Wv, wvb, n);
    cvt_f2bf<<<blocks, 256, 0, stream>>>(Wo, wob, n);
  }

  // projections into packed stacked (row remap), bf16 out
  for (int m = 0; m < 4; ++m) {
    int Mr = B * SL[m];
    dim3 grid(D / 128, (Mr + 127) / 128);
    gemm_proj<<<grid, 256, 0, stream>>>(x[m], Wm[m], bm[m], mod_emb + m * D,
                                        stacked, Mr, D, DIM[m], SL[m], OFFS[m], RPB);
  }

  // fused Q|K|V GEMM: [20336 x 3072] = stacked @ [Wq|Wk|Wv]^T
  {
    dim3 grid(24, (RROWS + 127) / 128);
    gemm_lds<0><<<grid, 256, 0, stream>>>(stacked, wqb, wkb, wvb, bq, bk, bv,
                                          qkv, RROWS, D, 3 * D);
  }

  // attention over window + mean over modalities -> fused (bf16)
  attn_fuse<<<(B * S) / 2, 256, 0, stream>>>(qkv, fusedb, bq, bk, bv, temp);

  // output GEMM: (B*S) x D, fp32 out
  {
    dim3 grid(8, (B * S) / 128);
    gemm_lds<1><<<grid, 256, 0, stream>>>(fusedb, wob, wob, wob, bo, bo, bo,
                                          d_out, B * S, D, D);
  }
}

// Round 5
// 565.228 us; speedup vs baseline: 1.5246x; 1.1499x over previous
//
#include <hip/hip_runtime.h>

typedef unsigned short u16;
typedef __bf16 bf16x8 __attribute__((ext_vector_type(8)));
typedef u16   u16x8  __attribute__((ext_vector_type(8)));
typedef float f32x4  __attribute__((ext_vector_type(4)));

// packed row layout: per batch, modality rows at OFFS[m], total RPB rows/batch
#define RPB 5084
#define SL0 2048
#define SL1 1024
#define SL2 1500
#define SL3 512

// ---------- helpers ----------
__device__ __forceinline__ u16 f2bf(float f) {
  union { float f; unsigned u; } x; x.f = f;
  unsigned u = x.u;
  u += 0x7fffu + ((u >> 16) & 1u);   // RNE
  return (u16)(u >> 16);
}
__device__ __forceinline__ float bf2f(u16 h) {
  union { unsigned u; float f; } x; x.u = ((unsigned)h) << 16;
  return x.f;
}
// async global->LDS, 16B per lane; dest = wave-uniform base + lane*16
__device__ __forceinline__ void gll16(const u16* g, u16* l) {
  __builtin_amdgcn_global_load_lds(
      (const __attribute__((address_space(1))) void*)g,
      (__attribute__((address_space(3))) void*)l, 16, 0, 0);
}

// ---------- fused fp32 -> bf16 conversion, 12 segments, one launch ----------
#define NSEG 12
struct CvtSegs {
  const float* src[NSEG];
  u16*         dst[NSEG];
  int          blk_end[NSEG];   // exclusive prefix of block counts (1024 elems/block)
  int          blk_base[NSEG];  // first block of segment
};
__global__ __launch_bounds__(256) void cvt_multi(CvtSegs segs) {
  int blk = blockIdx.x, seg = 0;
#pragma unroll
  for (int s = 0; s < NSEG; ++s) if (blk >= segs.blk_end[s]) seg = s + 1;
  const float* src = segs.src[seg];
  u16* dst = segs.dst[seg];
  int i = (blk - segs.blk_base[seg]) * 1024 + threadIdx.x * 4;
  f32x4 v = *(const f32x4*)(src + i);
  u16 o0 = f2bf(v[0]), o1 = f2bf(v[1]), o2 = f2bf(v[2]), o3 = f2bf(v[3]);
  u16* p = dst + i; p[0] = o0; p[1] = o1; p[2] = o2; p[3] = o3;
}

// ---------- m97-style bf16 GEMM via global_load_lds (QKV-fused / output) ----------
template<int STORE_F32>
__global__ __launch_bounds__(256) void gemm_lds(
    const u16* __restrict__ A,
    const u16* __restrict__ B0, const u16* __restrict__ B1, const u16* __restrict__ B2,
    const float* __restrict__ c0, const float* __restrict__ c1, const float* __restrict__ c2,
    void* __restrict__ Cout, int Mr, int K, int ldc)
{
  __shared__ u16 lA[128 * 32];
  __shared__ u16 lB[128 * 32];
  const int tid  = threadIdx.x;
  const int lane = tid & 63;
  const int wave = tid >> 6;
  const int wr   = (wave >> 1) * 64;
  const int wc   = (wave & 1) * 64;
  const int row0 = blockIdx.y * 128;

  const int wsel = blockIdx.x >> 3;          // which weight matrix
  const int colL = (blockIdx.x & 7) * 128;   // col offset within that W
  const u16*   Bw   = (wsel == 0) ? B0 : (wsel == 1) ? B1 : B2;
  const float* bias = (wsel == 0) ? c0 : (wsel == 1) ? c1 : c2;

  const int sr  = wave * 32 + (lane >> 2);
  const int sc  = (lane & 3) * 8;
  int ra0 = row0 + sr;      if (ra0 >= Mr) ra0 = Mr - 1;
  int ra1 = row0 + sr + 16; if (ra1 >= Mr) ra1 = Mr - 1;
  const u16* pA0 = A + (size_t)ra0 * K + sc;
  const u16* pA1 = A + (size_t)ra1 * K + sc;
  const u16* pB0 = Bw + (size_t)(colL + sr) * K + sc;
  const u16* pB1 = pB0 + (size_t)16 * K;
  u16* dA0 = &lA[(wave * 32) * 32];
  u16* dA1 = &lA[(wave * 32 + 16) * 32];
  u16* dB0 = &lB[(wave * 32) * 32];
  u16* dB1 = &lB[(wave * 32 + 16) * 32];

  f32x4 acc[4][4];
#pragma unroll
  for (int i = 0; i < 4; ++i)
#pragma unroll
    for (int j = 0; j < 4; ++j) acc[i][j] = f32x4{0.f, 0.f, 0.f, 0.f};

  const int fr = lane & 15;
  const int fk = (lane >> 4) * 8;

  for (int k0 = 0; k0 < K; k0 += 32) {
    __syncthreads();
    gll16(pA0 + k0, dA0);
    gll16(pA1 + k0, dA1);
    gll16(pB0 + k0, dB0);
    gll16(pB1 + k0, dB1);
    __syncthreads();

    bf16x8 af[4], bfr[4];
#pragma unroll
    for (int i = 0; i < 4; ++i)
      af[i] = *(const bf16x8*)&lA[(wr + i * 16 + fr) * 32 + fk];
#pragma unroll
    for (int j = 0; j < 4; ++j)
      bfr[j] = *(const bf16x8*)&lB[(wc + j * 16 + fr) * 32 + fk];
#pragma unroll
    for (int i = 0; i < 4; ++i)
#pragma unroll
      for (int j = 0; j < 4; ++j)
        acc[i][j] = __builtin_amdgcn_mfma_f32_16x16x32_bf16(af[i], bfr[j], acc[i][j], 0, 0, 0);
  }

  // epilogue: C/D layout col = lane&15, row = (lane>>4)*4 + reg  [m89/m91]
  const int fc = lane & 15;
  const int rq = (lane >> 4) * 4;
#pragma unroll
  for (int i = 0; i < 4; ++i) {
#pragma unroll
    for (int j = 0; j < 4; ++j) {
      const int cl = wc + j * 16 + fc;
      const float badd = bias[colL + cl];
      const int gc = blockIdx.x * 128 + cl;
#pragma unroll
      for (int reg = 0; reg < 4; ++reg) {
        int gr = row0 + wr + i * 16 + rq + reg;
        if (gr < Mr) {
          float v = acc[i][j][reg] + badd;
          if (STORE_F32) ((float*)Cout)[(size_t)gr * ldc + gc] = v;
          else           ((u16*)Cout)[(size_t)gr * ldc + gc] = f2bf(v);
        }
      }
    }
  }
}

// ---------- projection GEMM, same m97 structure: bf16 A/B, dual bias, row remap ----------
__global__ __launch_bounds__(256) void gemm_lds_p(
    const u16* __restrict__ A, const u16* __restrict__ Bw,
    const float* __restrict__ bias0, const float* __restrict__ bias1,
    u16* __restrict__ Cout, int Mr, int K,
    int sl, int obase, int obstride)
{
  __shared__ u16 lA[128 * 32];
  __shared__ u16 lB[128 * 32];
  const int tid  = threadIdx.x;
  const int lane = tid & 63;
  const int wave = tid >> 6;
  const int wr   = (wave >> 1) * 64;
  const int wc   = (wave & 1) * 64;
  const int row0 = blockIdx.y * 128;
  const int col0 = blockIdx.x * 128;

  const int sr  = wave * 32 + (lane >> 2);
  const int sc  = (lane & 3) * 8;
  int ra0 = row0 + sr;      if (ra0 >= Mr) ra0 = Mr - 1;
  int ra1 = row0 + sr + 16; if (ra1 >= Mr) ra1 = Mr - 1;
  const u16* pA0 = A + (size_t)ra0 * K + sc;
  const u16* pA1 = A + (size_t)ra1 * K + sc;
  const u16* pB0 = Bw + (size_t)(col0 + sr) * K + sc;
  const u16* pB1 = pB0 + (size_t)16 * K;
  u16* dA0 = &lA[(wave * 32) * 32];
  u16* dA1 = &lA[(wave * 32 + 16) * 32];
  u16* dB0 = &lB[(wave * 32) * 32];
  u16* dB1 = &lB[(wave * 32 + 16) * 32];

  f32x4 acc[4][4];
#pragma unroll
  for (int i = 0; i < 4; ++i)
#pragma unroll
    for (int j = 0; j < 4; ++j) acc[i][j] = f32x4{0.f, 0.f, 0.f, 0.f};

  const int fr = lane & 15;
  const int fk = (lane >> 4) * 8;

  for (int k0 = 0; k0 < K; k0 += 32) {
    __syncthreads();
    gll16(pA0 + k0, dA0);
    gll16(pA1 + k0, dA1);
    gll16(pB0 + k0, dB0);
    gll16(pB1 + k0, dB1);
    __syncthreads();

    bf16x8 af[4], bfr[4];
#pragma unroll
    for (int i = 0; i < 4; ++i)
      af[i] = *(const bf16x8*)&lA[(wr + i * 16 + fr) * 32 + fk];
#pragma unroll
    for (int j = 0; j < 4; ++j)
      bfr[j] = *(const bf16x8*)&lB[(wc + j * 16 + fr) * 32 + fk];
#pragma unroll
    for (int i = 0; i < 4; ++i)
#pragma unroll
      for (int j = 0; j < 4; ++j)
        acc[i][j] = __builtin_amdgcn_mfma_f32_16x16x32_bf16(af[i], bfr[j], acc[i][j], 0, 0, 0);
  }

  const int fc = lane & 15;
  const int rq = (lane >> 4) * 4;
#pragma unroll
  for (int i = 0; i < 4; ++i) {
#pragma unroll
    for (int j = 0; j < 4; ++j) {
      const int c = col0 + wc + j * 16 + fc;
      const float badd = bias0[c] + bias1[c];
#pragma unroll
      for (int reg = 0; reg < 4; ++reg) {
        int gr = row0 + wr + i * 16 + rq + reg;
        if (gr < Mr) {
          int bb = gr / sl, ss = gr - bb * sl;
          Cout[(size_t)(bb * obstride + obase + ss) * 1024 + c] = f2bf(acc[i][j][reg] + badd);
        }
      }
    }
  }
}

// ---------- windowed attention + mean over modalities ----------
// 8 lanes per head, bf16x8 per lane. ROUTES (IEEE-tie-corrected Cantor):
// m0:[0,1,2] m1:[0,1,2] m2:[2,3,0] m3:[3,2,0]
__global__ __launch_bounds__(256) void attn_fuse(
    const u16* __restrict__ QKV,   // [RROWS][3072]: Q|K|V
    u16* __restrict__ fused,
    const float* __restrict__ bq, const float* __restrict__ bk, const float* __restrict__ bv,
    const float* __restrict__ temp_ptr)
{
  const int ROUTE[4][3] = {{0,1,2},{0,1,2},{2,3,0},{3,2,0}};
  const int SLm[4]  = {SL0, SL1, SL2, SL3};
  const int OFFS[4] = {0, 2048, 3072, 4572};
  const int tid  = threadIdx.x;
  const int lane = tid & 63;
  const int wave = tid >> 6;
  const int bs   = blockIdx.x * 2 + (wave >> 1);
  const int s    = bs & 2047;
  const int b    = bs >> 11;
  const int h    = (wave & 1) * 8 + (lane >> 3);
  const int sub  = lane & 7;
  const int dbase = h * 64 + sub * 8;
  const float scale = 1.0f / (8.0f * fabsf(temp_ptr[0]));

  float acc[8];
#pragma unroll
  for (int i = 0; i < 8; ++i) acc[i] = 0.f;

#pragma unroll
  for (int m = 0; m < 4; ++m) {
    float qf[8];
    if (s < SLm[m]) {
      u16x8 q8 = *(const u16x8*)(QKV + ((size_t)(b * RPB + OFFS[m] + s)) * 3072 + dbase);
#pragma unroll
      for (int i = 0; i < 8; ++i) qf[i] = bf2f(q8[i]);
    } else {
#pragma unroll
      for (int i = 0; i < 8; ++i) qf[i] = bq[dbase + i];
    }
    float sc[3];
#pragma unroll
    for (int w = 0; w < 3; ++w) {
      const int r = ROUTE[m][w];
      float d = 0.f;
      if (s < SLm[r]) {
        u16x8 k8 = *(const u16x8*)(QKV + ((size_t)(b * RPB + OFFS[r] + s)) * 3072 + 1024 + dbase);
#pragma unroll
        for (int i = 0; i < 8; ++i) d += qf[i] * bf2f(k8[i]);
      } else {
#pragma unroll
        for (int i = 0; i < 8; ++i) d += qf[i] * bk[dbase + i];
      }
      d += __shfl_xor(d, 1, 64);
      d += __shfl_xor(d, 2, 64);
      d += __shfl_xor(d, 4, 64);
      sc[w] = d * scale;
    }
    float mx = fmaxf(sc[0], fmaxf(sc[1], sc[2]));
    float e0 = __expf(sc[0] - mx), e1 = __expf(sc[1] - mx), e2 = __expf(sc[2] - mx);
    float inv = 1.0f / (e0 + e1 + e2);
    float ws[3] = {e0 * inv, e1 * inv, e2 * inv};
#pragma unroll
    for (int w = 0; w < 3; ++w) {
      const int r = ROUTE[m][w];
      if (s < SLm[r]) {
        u16x8 v8 = *(const u16x8*)(QKV + ((size_t)(b * RPB + OFFS[r] + s)) * 3072 + 2048 + dbase);
#pragma unroll
        for (int i = 0; i < 8; ++i) acc[i] += ws[w] * bf2f(v8[i]);
      } else {
#pragma unroll
        for (int i = 0; i < 8; ++i) acc[i] += ws[w] * bv[dbase + i];
      }
    }
  }
  u16x8 o;
#pragma unroll
  for (int i = 0; i < 8; ++i) o[i] = f2bf(acc[i] * 0.25f);
  *(u16x8*)(fused + (size_t)bs * 1024 + dbase) = o;
}

// ---------- host orchestration ----------
extern "C" void kernel_launch(void* const* d_in, const int* in_sizes, int n_in,
                              void* d_out, int out_size, void* d_ws, size_t ws_size,
                              hipStream_t stream) {
  const int B = 4, S = 2048, D = 1024;
  const int SL[4]   = {SL0, SL1, SL2, SL3};
  const int DIM[4]  = {768, 1024, 512, 2048};
  const int OFFS[4] = {0, 2048, 3072, 4572};

  const float* x[4]  = {(const float*)d_in[0], (const float*)d_in[3], (const float*)d_in[6], (const float*)d_in[9]};
  const float* Wm[4] = {(const float*)d_in[1], (const float*)d_in[4], (const float*)d_in[7], (const float*)d_in[10]};
  const float* bm[4] = {(const float*)d_in[2], (const float*)d_in[5], (const float*)d_in[8], (const float*)d_in[11]};
  const float* mod_emb = (const float*)d_in[12];
  const float* Wq = (const float*)d_in[13]; const float* bq = (const float*)d_in[14];
  const float* Wk = (const float*)d_in[15]; const float* bk = (const float*)d_in[16];
  const float* Wv = (const float*)d_in[17]; const float* bv = (const float*)d_in[18];
  const float* Wo = (const float*)d_in[19]; const float* bo = (const float*)d_in[20];
  const float* temp = (const float*)d_in[21];

  const int RROWS = B * RPB;                 // 20336 real rows
  const size_t stackedB = ((size_t)RROWS * D * 2 + 255) / 256 * 256;
  const size_t qkvB     = ((size_t)RROWS * 3 * D * 2 + 255) / 256 * 256;
  const size_t wB       = ((size_t)D * D * 2 + 255) / 256 * 256;
  size_t wmB[4];
  for (int m = 0; m < 4; ++m) wmB[m] = ((size_t)D * DIM[m] * 2 + 255) / 256 * 256;
  const size_t need = stackedB + qkvB + 4 * wB + wmB[0] + wmB[1] + wmB[2] + wmB[3];
  if (ws_size < need) return;                // clean failure, not OOB crash

  char* p = (char*)d_ws;
  u16* stacked = (u16*)p;  p += stackedB;
  char* qkvbase = p;
  u16* qkv     = (u16*)p;  p += qkvB;
  u16* wqb     = (u16*)p;  p += wB;
  u16* wkb     = (u16*)p;  p += wB;
  u16* wvb     = (u16*)p;  p += wB;
  u16* wob     = (u16*)p;  p += wB;
  u16* wmb[4];
  for (int m = 0; m < 4; ++m) { wmb[m] = (u16*)p; p += wmB[m]; }
  u16* fusedb  = stacked;  // stacked dead after QKV GEMM

  // bf16 activations overlaid in the not-yet-live qkv buffer (dead once QKV GEMM writes)
  u16* xb[4];
  {
    char* q = qkvbase;
    for (int m = 0; m < 4; ++m) {
      xb[m] = (u16*)q;
      q += ((size_t)B * SL[m] * DIM[m] * 2 + 255) / 256 * 256;
    }
  }

  // single fused fp32->bf16 conversion: 4 x, 4 Wm, Wq, Wk, Wv, Wo
  {
    CvtSegs cs;
    const float* srcs[NSEG] = {x[0], x[1], x[2], x[3], Wm[0], Wm[1], Wm[2], Wm[3], Wq, Wk, Wv, Wo};
    u16* dsts[NSEG] = {xb[0], xb[1], xb[2], xb[3], wmb[0], wmb[1], wmb[2], wmb[3], wqb, wkb, wvb, wob};
    int ns[NSEG];
    for (int m = 0; m < 4; ++m) ns[m] = B * SL[m] * DIM[m];
    for (int m = 0; m < 4; ++m) ns[4 + m] = D * DIM[m];
    for (int i = 0; i < 4; ++i) ns[8 + i] = D * D;
    int base = 0;
    for (int i = 0; i < NSEG; ++i) {
      cs.src[i] = srcs[i]; cs.dst[i] = dsts[i];
      cs.blk_base[i] = base;
      base += (ns[i] + 1023) / 1024;
      cs.blk_end[i] = base;
    }
    cvt_multi<<<base, 256, 0, stream>>>(cs);
  }

  // projections into packed stacked (row remap), m97 structure
  for (int m = 0; m < 4; ++m) {
    int Mr = B * SL[m];
    dim3 grid(D / 128, (Mr + 127) / 128);
    gemm_lds_p<<<grid, 256, 0, stream>>>(xb[m], wmb[m], bm[m], mod_emb + m * D,
                                         stacked, Mr, DIM[m], SL[m], OFFS[m], RPB);
  }

  // fused Q|K|V GEMM: [20336 x 3072] = stacked @ [Wq|Wk|Wv]^T
  {
    dim3 grid(24, (RROWS + 127) / 128);
    gemm_lds<0><<<grid, 256, 0, stream>>>(stacked, wqb, wkb, wvb, bq, bk, bv,
                                          qkv, RROWS, D, 3 * D);
  }

  // attention over window + mean over modalities -> fused (bf16)
  attn_fuse<<<(B * S) / 2, 256, 0, stream>>>(qkv, fusedb, bq, bk, bv, temp);

  // output GEMM: (B*S) x D, fp32 out
  {
    dim3 grid(8, (B * S) / 128);
    gemm_lds<1><<<grid, 256, 0, stream>>>(fusedb, wob, wob, wob, bo, bo, bo,
                                          d_out, B * S, D, D);
  }
}

// Round 6
// 508.432 us; speedup vs baseline: 1.6949x; 1.1117x over previous
//
#include <hip/hip_runtime.h>

typedef unsigned short u16;
typedef __bf16 bf16x8 __attribute__((ext_vector_type(8)));
typedef u16   u16x8  __attribute__((ext_vector_type(8)));
typedef u16   u16x4  __attribute__((ext_vector_type(4)));
typedef float f32x4  __attribute__((ext_vector_type(4)));

// packed row layout: per batch, modality rows at OFFS[m], total RPB rows/batch
#define RPB 5084
#define SL0 2048
#define SL1 1024
#define SL2 1500
#define SL3 512

// ---------- helpers ----------
__device__ __forceinline__ u16 f2bf(float f) {
  union { float f; unsigned u; } x; x.f = f;
  unsigned u = x.u;
  u += 0x7fffu + ((u >> 16) & 1u);   // RNE
  return (u16)(u >> 16);
}
__device__ __forceinline__ float bf2f(u16 h) {
  union { unsigned u; float f; } x; x.u = ((unsigned)h) << 16;
  return x.f;
}
// async global->LDS, 16B per lane; dest = wave-uniform base + lane*16
__device__ __forceinline__ void gll16(const u16* g, u16* l) {
  __builtin_amdgcn_global_load_lds(
      (const __attribute__((address_space(1))) void*)g,
      (__attribute__((address_space(3))) void*)l, 16, 0, 0);
}

// ---------- fused fp32 -> bf16 conversion, 12 segments, one launch ----------
#define NSEG 12
struct CvtSegs {
  const float* src[NSEG];
  u16*         dst[NSEG];
  int          blk_end[NSEG];   // exclusive prefix of block counts (1024 elems/block)
  int          blk_base[NSEG];
};
__global__ __launch_bounds__(256) void cvt_multi(CvtSegs segs) {
  int blk = blockIdx.x, seg = 0;
#pragma unroll
  for (int s = 0; s < NSEG; ++s) if (blk >= segs.blk_end[s]) seg = s + 1;
  const float* src = segs.src[seg];
  u16* dst = segs.dst[seg];
  int i = (blk - segs.blk_base[seg]) * 1024 + threadIdx.x * 4;
  f32x4 v = *(const f32x4*)(src + i);
  u16x4 o;
  o[0] = f2bf(v[0]); o[1] = f2bf(v[1]); o[2] = f2bf(v[2]); o[3] = f2bf(v[3]);
  *(u16x4*)(dst + i) = o;   // one 8B store
}

// ---------- m97-style bf16 GEMM via global_load_lds (QKV-fused / output) ----------
template<int STORE_F32>
__global__ __launch_bounds__(256) void gemm_lds(
    const u16* __restrict__ A,
    const u16* __restrict__ B0, const u16* __restrict__ B1, const u16* __restrict__ B2,
    const float* __restrict__ c0, const float* __restrict__ c1, const float* __restrict__ c2,
    void* __restrict__ Cout, int Mr, int K, int ldc)
{
  __shared__ u16 lA[128 * 32];
  __shared__ u16 lB[128 * 32];
  const int tid  = threadIdx.x;
  const int lane = tid & 63;
  const int wave = tid >> 6;
  const int wr   = (wave >> 1) * 64;
  const int wc   = (wave & 1) * 64;
  const int row0 = blockIdx.y * 128;

  const int wsel = blockIdx.x >> 3;          // which weight matrix
  const int colL = (blockIdx.x & 7) * 128;   // col offset within that W
  const u16*   Bw   = (wsel == 0) ? B0 : (wsel == 1) ? B1 : B2;
  const float* bias = (wsel == 0) ? c0 : (wsel == 1) ? c1 : c2;

  const int sr  = wave * 32 + (lane >> 2);
  const int sc  = (lane & 3) * 8;
  int ra0 = row0 + sr;      if (ra0 >= Mr) ra0 = Mr - 1;
  int ra1 = row0 + sr + 16; if (ra1 >= Mr) ra1 = Mr - 1;
  const u16* pA0 = A + (size_t)ra0 * K + sc;
  const u16* pA1 = A + (size_t)ra1 * K + sc;
  const u16* pB0 = Bw + (size_t)(colL + sr) * K + sc;
  const u16* pB1 = pB0 + (size_t)16 * K;
  u16* dA0 = &lA[(wave * 32) * 32];
  u16* dA1 = &lA[(wave * 32 + 16) * 32];
  u16* dB0 = &lB[(wave * 32) * 32];
  u16* dB1 = &lB[(wave * 32 + 16) * 32];

  f32x4 acc[4][4];
#pragma unroll
  for (int i = 0; i < 4; ++i)
#pragma unroll
    for (int j = 0; j < 4; ++j) acc[i][j] = f32x4{0.f, 0.f, 0.f, 0.f};

  const int fr = lane & 15;
  const int fk = (lane >> 4) * 8;

  for (int k0 = 0; k0 < K; k0 += 32) {
    __syncthreads();
    gll16(pA0 + k0, dA0);
    gll16(pA1 + k0, dA1);
    gll16(pB0 + k0, dB0);
    gll16(pB1 + k0, dB1);
    __syncthreads();

    bf16x8 af[4], bfr[4];
#pragma unroll
    for (int i = 0; i < 4; ++i)
      af[i] = *(const bf16x8*)&lA[(wr + i * 16 + fr) * 32 + fk];
#pragma unroll
    for (int j = 0; j < 4; ++j)
      bfr[j] = *(const bf16x8*)&lB[(wc + j * 16 + fr) * 32 + fk];
#pragma unroll
    for (int i = 0; i < 4; ++i)
#pragma unroll
      for (int j = 0; j < 4; ++j)
        acc[i][j] = __builtin_amdgcn_mfma_f32_16x16x32_bf16(af[i], bfr[j], acc[i][j], 0, 0, 0);
  }

  // epilogue: C/D layout col = lane&15, row = (lane>>4)*4 + reg  [m89/m91]
  const int fc = lane & 15;
  const int rq = (lane >> 4) * 4;
#pragma unroll
  for (int i = 0; i < 4; ++i) {
#pragma unroll
    for (int j = 0; j < 4; ++j) {
      const int cl = wc + j * 16 + fc;
      const float badd = bias[colL + cl];
      const int gc = blockIdx.x * 128 + cl;
#pragma unroll
      for (int reg = 0; reg < 4; ++reg) {
        int gr = row0 + wr + i * 16 + rq + reg;
        if (gr < Mr) {
          float v = acc[i][j][reg] + badd;
          if (STORE_F32) ((float*)Cout)[(size_t)gr * ldc + gc] = v;
          else           ((u16*)Cout)[(size_t)gr * ldc + gc] = f2bf(v);
        }
      }
    }
  }
}

// ---------- ALL projections in ONE launch (segment table, grid-filling) ----------
// 1272 blocks total vs 4 serial launches of 512/256/376/128 (grid starvation fix)
struct ProjSegs {
  const u16*   A[4];
  const u16*   Bw[4];
  const float* b0[4];
  const float* b1[4];
  int Mr[4], K[4], sl[4], obase[4];
  int blk_end[4];   // exclusive prefix over blocks; seg m spans 8 * ceil(Mr/128) blocks
};
__global__ __launch_bounds__(256) void gemm_proj_all(ProjSegs ps, u16* __restrict__ Cout) {
  int blk = blockIdx.x, seg = 0;
#pragma unroll
  for (int s = 0; s < 3; ++s) if (blk >= ps.blk_end[s]) seg = s + 1;
  const int base  = seg ? ps.blk_end[seg - 1] : 0;
  const int local = blk - base;
  const int row0  = (local >> 3) * 128;
  const int col0  = (local & 7) * 128;
  const int Mr = ps.Mr[seg], K = ps.K[seg], sl = ps.sl[seg], obase = ps.obase[seg];
  const u16* A  = ps.A[seg];
  const u16* Bw = ps.Bw[seg];
  const float* bias0 = ps.b0[seg];
  const float* bias1 = ps.b1[seg];

  __shared__ u16 lA[128 * 32];
  __shared__ u16 lB[128 * 32];
  const int tid  = threadIdx.x;
  const int lane = tid & 63;
  const int wave = tid >> 6;
  const int wr   = (wave >> 1) * 64;
  const int wc   = (wave & 1) * 64;

  const int sr  = wave * 32 + (lane >> 2);
  const int sc  = (lane & 3) * 8;
  int ra0 = row0 + sr;      if (ra0 >= Mr) ra0 = Mr - 1;
  int ra1 = row0 + sr + 16; if (ra1 >= Mr) ra1 = Mr - 1;
  const u16* pA0 = A + (size_t)ra0 * K + sc;
  const u16* pA1 = A + (size_t)ra1 * K + sc;
  const u16* pB0 = Bw + (size_t)(col0 + sr) * K + sc;
  const u16* pB1 = pB0 + (size_t)16 * K;
  u16* dA0 = &lA[(wave * 32) * 32];
  u16* dA1 = &lA[(wave * 32 + 16) * 32];
  u16* dB0 = &lB[(wave * 32) * 32];
  u16* dB1 = &lB[(wave * 32 + 16) * 32];

  f32x4 acc[4][4];
#pragma unroll
  for (int i = 0; i < 4; ++i)
#pragma unroll
    for (int j = 0; j < 4; ++j) acc[i][j] = f32x4{0.f, 0.f, 0.f, 0.f};

  const int fr = lane & 15;
  const int fk = (lane >> 4) * 8;

  for (int k0 = 0; k0 < K; k0 += 32) {
    __syncthreads();
    gll16(pA0 + k0, dA0);
    gll16(pA1 + k0, dA1);
    gll16(pB0 + k0, dB0);
    gll16(pB1 + k0, dB1);
    __syncthreads();

    bf16x8 af[4], bfr[4];
#pragma unroll
    for (int i = 0; i < 4; ++i)
      af[i] = *(const bf16x8*)&lA[(wr + i * 16 + fr) * 32 + fk];
#pragma unroll
    for (int j = 0; j < 4; ++j)
      bfr[j] = *(const bf16x8*)&lB[(wc + j * 16 + fr) * 32 + fk];
#pragma unroll
    for (int i = 0; i < 4; ++i)
#pragma unroll
      for (int j = 0; j < 4; ++j)
        acc[i][j] = __builtin_amdgcn_mfma_f32_16x16x32_bf16(af[i], bfr[j], acc[i][j], 0, 0, 0);
  }

  const int fc = lane & 15;
  const int rq = (lane >> 4) * 4;
#pragma unroll
  for (int i = 0; i < 4; ++i) {
#pragma unroll
    for (int j = 0; j < 4; ++j) {
      const int c = col0 + wc + j * 16 + fc;
      const float badd = bias0[c] + bias1[c];
#pragma unroll
      for (int reg = 0; reg < 4; ++reg) {
        int gr = row0 + wr + i * 16 + rq + reg;
        if (gr < Mr) {
          int bb = gr / sl, ss = gr - bb * sl;
          Cout[(size_t)(bb * RPB + obase + ss) * 1024 + c] = f2bf(acc[i][j][reg] + badd);
        }
      }
    }
  }
}

// ---------- windowed attention + mean over modalities ----------
// 8 lanes per head, bf16x8 per lane. ROUTES (IEEE-tie-corrected Cantor):
// m0:[0,1,2] m1:[0,1,2] m2:[2,3,0] m3:[3,2,0]
__global__ __launch_bounds__(256) void attn_fuse(
    const u16* __restrict__ QKV,   // [RROWS][3072]: Q|K|V
    u16* __restrict__ fused,
    const float* __restrict__ bq, const float* __restrict__ bk, const float* __restrict__ bv,
    const float* __restrict__ temp_ptr)
{
  const int ROUTE[4][3] = {{0,1,2},{0,1,2},{2,3,0},{3,2,0}};
  const int SLm[4]  = {SL0, SL1, SL2, SL3};
  const int OFFS[4] = {0, 2048, 3072, 4572};
  const int tid  = threadIdx.x;
  const int lane = tid & 63;
  const int wave = tid >> 6;
  const int bs   = blockIdx.x * 2 + (wave >> 1);
  const int s    = bs & 2047;
  const int b    = bs >> 11;
  const int h    = (wave & 1) * 8 + (lane >> 3);
  const int sub  = lane & 7;
  const int dbase = h * 64 + sub * 8;
  const float scale = 1.0f / (8.0f * fabsf(temp_ptr[0]));

  float acc[8];
#pragma unroll
  for (int i = 0; i < 8; ++i) acc[i] = 0.f;

#pragma unroll
  for (int m = 0; m < 4; ++m) {
    float qf[8];
    if (s < SLm[m]) {
      u16x8 q8 = *(const u16x8*)(QKV + ((size_t)(b * RPB + OFFS[m] + s)) * 3072 + dbase);
#pragma unroll
      for (int i = 0; i < 8; ++i) qf[i] = bf2f(q8[i]);
    } else {
#pragma unroll
      for (int i = 0; i < 8; ++i) qf[i] = bq[dbase + i];
    }
    float sc[3];
#pragma unroll
    for (int w = 0; w < 3; ++w) {
      const int r = ROUTE[m][w];
      float d = 0.f;
      if (s < SLm[r]) {
        u16x8 k8 = *(const u16x8*)(QKV + ((size_t)(b * RPB + OFFS[r] + s)) * 3072 + 1024 + dbase);
#pragma unroll
        for (int i = 0; i < 8; ++i) d += qf[i] * bf2f(k8[i]);
      } else {
#pragma unroll
        for (int i = 0; i < 8; ++i) d += qf[i] * bk[dbase + i];
      }
      d += __shfl_xor(d, 1, 64);
      d += __shfl_xor(d, 2, 64);
      d += __shfl_xor(d, 4, 64);
      sc[w] = d * scale;
    }
    float mx = fmaxf(sc[0], fmaxf(sc[1], sc[2]));
    float e0 = __expf(sc[0] - mx), e1 = __expf(sc[1] - mx), e2 = __expf(sc[2] - mx);
    float inv = 1.0f / (e0 + e1 + e2);
    float ws[3] = {e0 * inv, e1 * inv, e2 * inv};
#pragma unroll
    for (int w = 0; w < 3; ++w) {
      const int r = ROUTE[m][w];
      if (s < SLm[r]) {
        u16x8 v8 = *(const u16x8*)(QKV + ((size_t)(b * RPB + OFFS[r] + s)) * 3072 + 2048 + dbase);
#pragma unroll
        for (int i = 0; i < 8; ++i) acc[i] += ws[w] * bf2f(v8[i]);
      } else {
#pragma unroll
        for (int i = 0; i < 8; ++i) acc[i] += ws[w] * bv[dbase + i];
      }
    }
  }
  u16x8 o;
#pragma unroll
  for (int i = 0; i < 8; ++i) o[i] = f2bf(acc[i] * 0.25f);
  *(u16x8*)(fused + (size_t)bs * 1024 + dbase) = o;
}

// ---------- host orchestration ----------
extern "C" void kernel_launch(void* const* d_in, const int* in_sizes, int n_in,
                              void* d_out, int out_size, void* d_ws, size_t ws_size,
                              hipStream_t stream) {
  const int B = 4, S = 2048, D = 1024;
  const int SL[4]   = {SL0, SL1, SL2, SL3};
  const int DIM[4]  = {768, 1024, 512, 2048};
  const int OFFS[4] = {0, 2048, 3072, 4572};

  const float* x[4]  = {(const float*)d_in[0], (const float*)d_in[3], (const float*)d_in[6], (const float*)d_in[9]};
  const float* Wm[4] = {(const float*)d_in[1], (const float*)d_in[4], (const float*)d_in[7], (const float*)d_in[10]};
  const float* bm[4] = {(const float*)d_in[2], (const float*)d_in[5], (const float*)d_in[8], (const float*)d_in[11]};
  const float* mod_emb = (const float*)d_in[12];
  const float* Wq = (const float*)d_in[13]; const float* bq = (const float*)d_in[14];
  const float* Wk = (const float*)d_in[15]; const float* bk = (const float*)d_in[16];
  const float* Wv = (const float*)d_in[17]; const float* bv = (const float*)d_in[18];
  const float* Wo = (const float*)d_in[19]; const float* bo = (const float*)d_in[20];
  const float* temp = (const float*)d_in[21];

  const int RROWS = B * RPB;                 // 20336 real rows
  const size_t stackedB = ((size_t)RROWS * D * 2 + 255) / 256 * 256;
  const size_t qkvB     = ((size_t)RROWS * 3 * D * 2 + 255) / 256 * 256;
  const size_t wB       = ((size_t)D * D * 2 + 255) / 256 * 256;
  size_t wmB[4];
  for (int m = 0; m < 4; ++m) wmB[m] = ((size_t)D * DIM[m] * 2 + 255) / 256 * 256;
  const size_t need = stackedB + qkvB + 4 * wB + wmB[0] + wmB[1] + wmB[2] + wmB[3];
  if (ws_size < need) return;                // clean failure, not OOB crash

  char* p = (char*)d_ws;
  u16* stacked = (u16*)p;  p += stackedB;
  char* qkvbase = p;
  u16* qkv     = (u16*)p;  p += qkvB;
  u16* wqb     = (u16*)p;  p += wB;
  u16* wkb     = (u16*)p;  p += wB;
  u16* wvb     = (u16*)p;  p += wB;
  u16* wob     = (u16*)p;  p += wB;
  u16* wmb[4];
  for (int m = 0; m < 4; ++m) { wmb[m] = (u16*)p; p += wmB[m]; }
  u16* fusedb  = stacked;  // stacked dead after QKV GEMM

  // bf16 activations overlaid in the not-yet-live qkv buffer (dead once QKV GEMM writes)
  u16* xb[4];
  {
    char* q = qkvbase;
    for (int m = 0; m < 4; ++m) {
      xb[m] = (u16*)q;
      q += ((size_t)B * SL[m] * DIM[m] * 2 + 255) / 256 * 256;
    }
  }

  // single fused fp32->bf16 conversion: 4 x, 4 Wm, Wq, Wk, Wv, Wo
  {
    CvtSegs cs;
    const float* srcs[NSEG] = {x[0], x[1], x[2], x[3], Wm[0], Wm[1], Wm[2], Wm[3], Wq, Wk, Wv, Wo};
    u16* dsts[NSEG] = {xb[0], xb[1], xb[2], xb[3], wmb[0], wmb[1], wmb[2], wmb[3], wqb, wkb, wvb, wob};
    int ns[NSEG];
    for (int m = 0; m < 4; ++m) ns[m] = B * SL[m] * DIM[m];
    for (int m = 0; m < 4; ++m) ns[4 + m] = D * DIM[m];
    for (int i = 0; i < 4; ++i) ns[8 + i] = D * D;
    int base = 0;
    for (int i = 0; i < NSEG; ++i) {
      cs.src[i] = srcs[i]; cs.dst[i] = dsts[i];
      cs.blk_base[i] = base;
      base += (ns[i] + 1023) / 1024;
      cs.blk_end[i] = base;
    }
    cvt_multi<<<base, 256, 0, stream>>>(cs);
  }

  // ALL projections in one grid-filling launch
  {
    ProjSegs ps;
    int base = 0;
    for (int m = 0; m < 4; ++m) {
      int Mr = B * SL[m];
      ps.A[m] = xb[m]; ps.Bw[m] = wmb[m];
      ps.b0[m] = bm[m]; ps.b1[m] = mod_emb + m * D;
      ps.Mr[m] = Mr; ps.K[m] = DIM[m]; ps.sl[m] = SL[m]; ps.obase[m] = OFFS[m];
      base += 8 * ((Mr + 127) / 128);
      ps.blk_end[m] = base;
    }
    gemm_proj_all<<<base, 256, 0, stream>>>(ps, stacked);
  }

  // fused Q|K|V GEMM: [20336 x 3072] = stacked @ [Wq|Wk|Wv]^T
  {
    dim3 grid(24, (RROWS + 127) / 128);
    gemm_lds<0><<<grid, 256, 0, stream>>>(stacked, wqb, wkb, wvb, bq, bk, bv,
                                          qkv, RROWS, D, 3 * D);
  }

  // attention over window + mean over modalities -> fused (bf16)
  attn_fuse<<<(B * S) / 2, 256, 0, stream>>>(qkv, fusedb, bq, bk, bv, temp);

  // output GEMM: (B*S) x D, fp32 out
  {
    dim3 grid(8, (B * S) / 128);
    gemm_lds<1><<<grid, 256, 0, stream>>>(fusedb, wob, wob, wob, bo, bo, bo,
                                          d_out, B * S, D, D);
  }
}

// Round 7
// 458.240 us; speedup vs baseline: 1.8806x; 1.1095x over previous
//
#include <hip/hip_runtime.h>

typedef unsigned short u16;
typedef __bf16 bf16x8 __attribute__((ext_vector_type(8)));
typedef u16   u16x8  __attribute__((ext_vector_type(8)));
typedef u16   u16x4  __attribute__((ext_vector_type(4)));
typedef float f32x4  __attribute__((ext_vector_type(4)));

// packed row layout: per batch, modality rows at OFFS[m], total RPB rows/batch
#define RPB 5084
#define SL0 2048
#define SL1 1024
#define SL2 1500
#define SL3 512

// ---------- helpers ----------
__device__ __forceinline__ u16 f2bf(float f) {
  union { float f; unsigned u; } x; x.f = f;
  unsigned u = x.u;
  u += 0x7fffu + ((u >> 16) & 1u);   // RNE
  return (u16)(u >> 16);
}
__device__ __forceinline__ float bf2f(u16 h) {
  union { unsigned u; float f; } x; x.u = ((unsigned)h) << 16;
  return x.f;
}
// async global->LDS, 16B per lane; dest = wave-uniform base + lane*16
__device__ __forceinline__ void gll16(const u16* g, u16* l) {
  __builtin_amdgcn_global_load_lds(
      (const __attribute__((address_space(1))) void*)g,
      (__attribute__((address_space(3))) void*)l, 16, 0, 0);
}

// ---------- fused fp32 -> bf16 conversion, 12 segments, one launch ----------
#define NSEG 12
struct CvtSegs {
  const float* src[NSEG];
  u16*         dst[NSEG];
  int          blk_end[NSEG];
  int          blk_base[NSEG];
};
__global__ __launch_bounds__(256) void cvt_multi(CvtSegs segs) {
  int blk = blockIdx.x, seg = 0;
#pragma unroll
  for (int s = 0; s < NSEG; ++s) if (blk >= segs.blk_end[s]) seg = s + 1;
  const float* src = segs.src[seg];
  u16* dst = segs.dst[seg];
  int i = (blk - segs.blk_base[seg]) * 1024 + threadIdx.x * 4;
  f32x4 v = *(const f32x4*)(src + i);
  u16x4 o;
  o[0] = f2bf(v[0]); o[1] = f2bf(v[1]); o[2] = f2bf(v[2]); o[3] = f2bf(v[3]);
  *(u16x4*)(dst + i) = o;
}

// ---------- BK=64 MFMA K-step shared by all GEMMs ----------
// Dual 32-col LDS buffers keep the bank-safe [row][32] geometry (64B rows ->
// 2-way alias only) while halving the barrier count vs BK=32. Accumulation
// order over k is unchanged -> bit-identical results vs BK=32.

// ---------- m97-style bf16 GEMM via global_load_lds (QKV-fused / output) ----------
template<int STORE_F32>
__global__ __launch_bounds__(256) void gemm_lds(
    const u16* __restrict__ A,
    const u16* __restrict__ B0, const u16* __restrict__ B1, const u16* __restrict__ B2,
    const float* __restrict__ c0, const float* __restrict__ c1, const float* __restrict__ c2,
    void* __restrict__ Cout, int Mr, int K, int ldc)
{
  __shared__ u16 lA0[128 * 32], lA1[128 * 32];
  __shared__ u16 lB0[128 * 32], lB1[128 * 32];
  const int tid  = threadIdx.x;
  const int lane = tid & 63;
  const int wave = tid >> 6;
  const int wr   = (wave >> 1) * 64;
  const int wc   = (wave & 1) * 64;
  const int row0 = blockIdx.y * 128;

  const int wsel = blockIdx.x >> 3;
  const int colL = (blockIdx.x & 7) * 128;
  const u16*   Bw   = (wsel == 0) ? B0 : (wsel == 1) ? B1 : B2;
  const float* bias = (wsel == 0) ? c0 : (wsel == 1) ? c1 : c2;

  const int sr  = wave * 32 + (lane >> 2);
  const int sc  = (lane & 3) * 8;
  int ra0 = row0 + sr;      if (ra0 >= Mr) ra0 = Mr - 1;
  int ra1 = row0 + sr + 16; if (ra1 >= Mr) ra1 = Mr - 1;
  const u16* pA0 = A + (size_t)ra0 * K + sc;
  const u16* pA1 = A + (size_t)ra1 * K + sc;
  const u16* pB0 = Bw + (size_t)(colL + sr) * K + sc;
  const u16* pB1 = pB0 + (size_t)16 * K;
  u16* dA0a = &lA0[(wave * 32) * 32];      u16* dA1a = &lA0[(wave * 32 + 16) * 32];
  u16* dA0b = &lA1[(wave * 32) * 32];      u16* dA1b = &lA1[(wave * 32 + 16) * 32];
  u16* dB0a = &lB0[(wave * 32) * 32];      u16* dB1a = &lB0[(wave * 32 + 16) * 32];
  u16* dB0b = &lB1[(wave * 32) * 32];      u16* dB1b = &lB1[(wave * 32 + 16) * 32];

  f32x4 acc[4][4];
#pragma unroll
  for (int i = 0; i < 4; ++i)
#pragma unroll
    for (int j = 0; j < 4; ++j) acc[i][j] = f32x4{0.f, 0.f, 0.f, 0.f};

  const int fr = lane & 15;
  const int fk = (lane >> 4) * 8;

  for (int k0 = 0; k0 < K; k0 += 64) {
    __syncthreads();
    gll16(pA0 + k0, dA0a);       gll16(pA1 + k0, dA1a);
    gll16(pB0 + k0, dB0a);       gll16(pB1 + k0, dB1a);
    gll16(pA0 + k0 + 32, dA0b);  gll16(pA1 + k0 + 32, dA1b);
    gll16(pB0 + k0 + 32, dB0b);  gll16(pB1 + k0 + 32, dB1b);
    __syncthreads();

    bf16x8 af[4], bfr[4];
#pragma unroll
    for (int i = 0; i < 4; ++i)
      af[i] = *(const bf16x8*)&lA0[(wr + i * 16 + fr) * 32 + fk];
#pragma unroll
    for (int j = 0; j < 4; ++j)
      bfr[j] = *(const bf16x8*)&lB0[(wc + j * 16 + fr) * 32 + fk];
#pragma unroll
    for (int i = 0; i < 4; ++i)
#pragma unroll
      for (int j = 0; j < 4; ++j)
        acc[i][j] = __builtin_amdgcn_mfma_f32_16x16x32_bf16(af[i], bfr[j], acc[i][j], 0, 0, 0);
#pragma unroll
    for (int i = 0; i < 4; ++i)
      af[i] = *(const bf16x8*)&lA1[(wr + i * 16 + fr) * 32 + fk];
#pragma unroll
    for (int j = 0; j < 4; ++j)
      bfr[j] = *(const bf16x8*)&lB1[(wc + j * 16 + fr) * 32 + fk];
#pragma unroll
    for (int i = 0; i < 4; ++i)
#pragma unroll
      for (int j = 0; j < 4; ++j)
        acc[i][j] = __builtin_amdgcn_mfma_f32_16x16x32_bf16(af[i], bfr[j], acc[i][j], 0, 0, 0);
  }

  // epilogue: C/D layout col = lane&15, row = (lane>>4)*4 + reg  [m89/m91]
  const int fc = lane & 15;
  const int rq = (lane >> 4) * 4;
#pragma unroll
  for (int i = 0; i < 4; ++i) {
#pragma unroll
    for (int j = 0; j < 4; ++j) {
      const int cl = wc + j * 16 + fc;
      const float badd = bias[colL + cl];
      const int gc = blockIdx.x * 128 + cl;
#pragma unroll
      for (int reg = 0; reg < 4; ++reg) {
        int gr = row0 + wr + i * 16 + rq + reg;
        if (gr < Mr) {
          float v = acc[i][j][reg] + badd;
          if (STORE_F32) ((float*)Cout)[(size_t)gr * ldc + gc] = v;
          else           ((u16*)Cout)[(size_t)gr * ldc + gc] = f2bf(v);
        }
      }
    }
  }
}

// ---------- ALL projections in ONE launch (segment table, longest-K first) ----------
struct ProjSegs {
  const u16*   A[4];
  const u16*   Bw[4];
  const float* b0[4];
  const float* b1[4];
  int Mr[4], K[4], sl[4], obase[4];
  int blk_end[4];
};
__global__ __launch_bounds__(256) void gemm_proj_all(ProjSegs ps, u16* __restrict__ Cout) {
  int blk = blockIdx.x, seg = 0;
#pragma unroll
  for (int s = 0; s < 3; ++s) if (blk >= ps.blk_end[s]) seg = s + 1;
  const int base  = seg ? ps.blk_end[seg - 1] : 0;
  const int local = blk - base;
  const int row0  = (local >> 3) * 128;
  const int col0  = (local & 7) * 128;
  const int Mr = ps.Mr[seg], K = ps.K[seg], sl = ps.sl[seg], obase = ps.obase[seg];
  const u16* A  = ps.A[seg];
  const u16* Bw = ps.Bw[seg];
  const float* bias0 = ps.b0[seg];
  const float* bias1 = ps.b1[seg];

  __shared__ u16 lA0[128 * 32], lA1[128 * 32];
  __shared__ u16 lB0[128 * 32], lB1[128 * 32];
  const int tid  = threadIdx.x;
  const int lane = tid & 63;
  const int wave = tid >> 6;
  const int wr   = (wave >> 1) * 64;
  const int wc   = (wave & 1) * 64;

  const int sr  = wave * 32 + (lane >> 2);
  const int sc  = (lane & 3) * 8;
  int ra0 = row0 + sr;      if (ra0 >= Mr) ra0 = Mr - 1;
  int ra1 = row0 + sr + 16; if (ra1 >= Mr) ra1 = Mr - 1;
  const u16* pA0 = A + (size_t)ra0 * K + sc;
  const u16* pA1 = A + (size_t)ra1 * K + sc;
  const u16* pB0 = Bw + (size_t)(col0 + sr) * K + sc;
  const u16* pB1 = pB0 + (size_t)16 * K;
  u16* dA0a = &lA0[(wave * 32) * 32];      u16* dA1a = &lA0[(wave * 32 + 16) * 32];
  u16* dA0b = &lA1[(wave * 32) * 32];      u16* dA1b = &lA1[(wave * 32 + 16) * 32];
  u16* dB0a = &lB0[(wave * 32) * 32];      u16* dB1a = &lB0[(wave * 32 + 16) * 32];
  u16* dB0b = &lB1[(wave * 32) * 32];      u16* dB1b = &lB1[(wave * 32 + 16) * 32];

  f32x4 acc[4][4];
#pragma unroll
  for (int i = 0; i < 4; ++i)
#pragma unroll
    for (int j = 0; j < 4; ++j) acc[i][j] = f32x4{0.f, 0.f, 0.f, 0.f};

  const int fr = lane & 15;
  const int fk = (lane >> 4) * 8;

  for (int k0 = 0; k0 < K; k0 += 64) {
    __syncthreads();
    gll16(pA0 + k0, dA0a);       gll16(pA1 + k0, dA1a);
    gll16(pB0 + k0, dB0a);       gll16(pB1 + k0, dB1a);
    gll16(pA0 + k0 + 32, dA0b);  gll16(pA1 + k0 + 32, dA1b);
    gll16(pB0 + k0 + 32, dB0b);  gll16(pB1 + k0 + 32, dB1b);
    __syncthreads();

    bf16x8 af[4], bfr[4];
#pragma unroll
    for (int i = 0; i < 4; ++i)
      af[i] = *(const bf16x8*)&lA0[(wr + i * 16 + fr) * 32 + fk];
#pragma unroll
    for (int j = 0; j < 4; ++j)
      bfr[j] = *(const bf16x8*)&lB0[(wc + j * 16 + fr) * 32 + fk];
#pragma unroll
    for (int i = 0; i < 4; ++i)
#pragma unroll
      for (int j = 0; j < 4; ++j)
        acc[i][j] = __builtin_amdgcn_mfma_f32_16x16x32_bf16(af[i], bfr[j], acc[i][j], 0, 0, 0);
#pragma unroll
    for (int i = 0; i < 4; ++i)
      af[i] = *(const bf16x8*)&lA1[(wr + i * 16 + fr) * 32 + fk];
#pragma unroll
    for (int j = 0; j < 4; ++j)
      bfr[j] = *(const bf16x8*)&lB1[(wc + j * 16 + fr) * 32 + fk];
#pragma unroll
    for (int i = 0; i < 4; ++i)
#pragma unroll
      for (int j = 0; j < 4; ++j)
        acc[i][j] = __builtin_amdgcn_mfma_f32_16x16x32_bf16(af[i], bfr[j], acc[i][j], 0, 0, 0);
  }

  const int fc = lane & 15;
  const int rq = (lane >> 4) * 4;
#pragma unroll
  for (int i = 0; i < 4; ++i) {
#pragma unroll
    for (int j = 0; j < 4; ++j) {
      const int c = col0 + wc + j * 16 + fc;
      const float badd = bias0[c] + bias1[c];
#pragma unroll
      for (int reg = 0; reg < 4; ++reg) {
        int gr = row0 + wr + i * 16 + rq + reg;
        if (gr < Mr) {
          int bb = gr / sl, ss = gr - bb * sl;
          Cout[(size_t)(bb * RPB + obase + ss) * 1024 + c] = f2bf(acc[i][j][reg] + badd);
        }
      }
    }
  }
}

// ---------- windowed attention + mean over modalities ----------
// Preload Q/K/V rows of all 4 modalities ONCE into registers (route multiset
// reuses r=0,r=2 four times; old code loaded K/V 12x instead of 4x).
// ROUTES (IEEE-tie-corrected Cantor): m0:[0,1,2] m1:[0,1,2] m2:[2,3,0] m3:[3,2,0]
__global__ __launch_bounds__(256) void attn_fuse(
    const u16* __restrict__ QKV,   // [RROWS][3072]: Q|K|V
    u16* __restrict__ fused,
    const float* __restrict__ bq, const float* __restrict__ bk, const float* __restrict__ bv,
    const float* __restrict__ temp_ptr)
{
  const int ROUTE[4][3] = {{0,1,2},{0,1,2},{2,3,0},{3,2,0}};
  const int SLm[4]  = {SL0, SL1, SL2, SL3};
  const int OFFS[4] = {0, 2048, 3072, 4572};
  const int tid  = threadIdx.x;
  const int lane = tid & 63;
  const int wave = tid >> 6;
  const int bs   = blockIdx.x * 2 + (wave >> 1);
  const int s    = bs & 2047;
  const int b    = bs >> 11;
  const int h    = (wave & 1) * 8 + (lane >> 3);
  const int sub  = lane & 7;
  const int dbase = h * 64 + sub * 8;
  const float scale = 1.0f / (8.0f * fabsf(temp_ptr[0]));

  float qf[4][8], kf[4][8], vf[4][8];
#pragma unroll
  for (int r = 0; r < 4; ++r) {
    if (s < SLm[r]) {
      const u16* base = QKV + ((size_t)(b * RPB + OFFS[r] + s)) * 3072 + dbase;
      u16x8 q8 = *(const u16x8*)(base);
      u16x8 k8 = *(const u16x8*)(base + 1024);
      u16x8 v8 = *(const u16x8*)(base + 2048);
#pragma unroll
      for (int i = 0; i < 8; ++i) {
        qf[r][i] = bf2f(q8[i]); kf[r][i] = bf2f(k8[i]); vf[r][i] = bf2f(v8[i]);
      }
    } else {
#pragma unroll
      for (int i = 0; i < 8; ++i) {
        qf[r][i] = bq[dbase + i]; kf[r][i] = bk[dbase + i]; vf[r][i] = bv[dbase + i];
      }
    }
  }

  float acc[8];
#pragma unroll
  for (int i = 0; i < 8; ++i) acc[i] = 0.f;

#pragma unroll
  for (int m = 0; m < 4; ++m) {
    float sc[3];
#pragma unroll
    for (int w = 0; w < 3; ++w) {
      const int r = ROUTE[m][w];
      float d = 0.f;
#pragma unroll
      for (int i = 0; i < 8; ++i) d += qf[m][i] * kf[r][i];
      d += __shfl_xor(d, 1, 64);
      d += __shfl_xor(d, 2, 64);
      d += __shfl_xor(d, 4, 64);
      sc[w] = d * scale;
    }
    float mx = fmaxf(sc[0], fmaxf(sc[1], sc[2]));
    float e0 = __expf(sc[0] - mx), e1 = __expf(sc[1] - mx), e2 = __expf(sc[2] - mx);
    float inv = 1.0f / (e0 + e1 + e2);
    float ws[3] = {e0 * inv, e1 * inv, e2 * inv};
#pragma unroll
    for (int w = 0; w < 3; ++w) {
      const int r = ROUTE[m][w];
#pragma unroll
      for (int i = 0; i < 8; ++i) acc[i] += ws[w] * vf[r][i];
    }
  }
  u16x8 o;
#pragma unroll
  for (int i = 0; i < 8; ++i) o[i] = f2bf(acc[i] * 0.25f);
  *(u16x8*)(fused + (size_t)bs * 1024 + dbase) = o;
}

// ---------- host orchestration ----------
extern "C" void kernel_launch(void* const* d_in, const int* in_sizes, int n_in,
                              void* d_out, int out_size, void* d_ws, size_t ws_size,
                              hipStream_t stream) {
  const int B = 4, S = 2048, D = 1024;
  const int SL[4]   = {SL0, SL1, SL2, SL3};
  const int DIM[4]  = {768, 1024, 512, 2048};
  const int OFFS[4] = {0, 2048, 3072, 4572};

  const float* x[4]  = {(const float*)d_in[0], (const float*)d_in[3], (const float*)d_in[6], (const float*)d_in[9]};
  const float* Wm[4] = {(const float*)d_in[1], (const float*)d_in[4], (const float*)d_in[7], (const float*)d_in[10]};
  const float* bm[4] = {(const float*)d_in[2], (const float*)d_in[5], (const float*)d_in[8], (const float*)d_in[11]};
  const float* mod_emb = (const float*)d_in[12];
  const float* Wq = (const float*)d_in[13]; const float* bq = (const float*)d_in[14];
  const float* Wk = (const float*)d_in[15]; const float* bk = (const float*)d_in[16];
  const float* Wv = (const float*)d_in[17]; const float* bv = (const float*)d_in[18];
  const float* Wo = (const float*)d_in[19]; const float* bo = (const float*)d_in[20];
  const float* temp = (const float*)d_in[21];

  const int RROWS = B * RPB;                 // 20336 real rows
  const size_t stackedB = ((size_t)RROWS * D * 2 + 255) / 256 * 256;
  const size_t qkvB     = ((size_t)RROWS * 3 * D * 2 + 255) / 256 * 256;
  const size_t wB       = ((size_t)D * D * 2 + 255) / 256 * 256;
  size_t wmB[4];
  for (int m = 0; m < 4; ++m) wmB[m] = ((size_t)D * DIM[m] * 2 + 255) / 256 * 256;
  const size_t need = stackedB + qkvB + 4 * wB + wmB[0] + wmB[1] + wmB[2] + wmB[3];
  if (ws_size < need) return;                // clean failure, not OOB crash

  char* p = (char*)d_ws;
  u16* stacked = (u16*)p;  p += stackedB;
  char* qkvbase = p;
  u16* qkv     = (u16*)p;  p += qkvB;
  u16* wqb     = (u16*)p;  p += wB;
  u16* wkb     = (u16*)p;  p += wB;
  u16* wvb     = (u16*)p;  p += wB;
  u16* wob     = (u16*)p;  p += wB;
  u16* wmb[4];
  for (int m = 0; m < 4; ++m) { wmb[m] = (u16*)p; p += wmB[m]; }
  u16* fusedb  = stacked;  // stacked dead after QKV GEMM

  // bf16 activations overlaid in the not-yet-live qkv buffer
  u16* xb[4];
  {
    char* q = qkvbase;
    for (int m = 0; m < 4; ++m) {
      xb[m] = (u16*)q;
      q += ((size_t)B * SL[m] * DIM[m] * 2 + 255) / 256 * 256;
    }
  }

  // single fused fp32->bf16 conversion
  {
    CvtSegs cs;
    const float* srcs[NSEG] = {x[0], x[1], x[2], x[3], Wm[0], Wm[1], Wm[2], Wm[3], Wq, Wk, Wv, Wo};
    u16* dsts[NSEG] = {xb[0], xb[1], xb[2], xb[3], wmb[0], wmb[1], wmb[2], wmb[3], wqb, wkb, wvb, wob};
    int ns[NSEG];
    for (int m = 0; m < 4; ++m) ns[m] = B * SL[m] * DIM[m];
    for (int m = 0; m < 4; ++m) ns[4 + m] = D * DIM[m];
    for (int i = 0; i < 4; ++i) ns[8 + i] = D * D;
    int base = 0;
    for (int i = 0; i < NSEG; ++i) {
      cs.src[i] = srcs[i]; cs.dst[i] = dsts[i];
      cs.blk_base[i] = base;
      base += (ns[i] + 1023) / 1024;
      cs.blk_end[i] = base;
    }
    cvt_multi<<<base, 256, 0, stream>>>(cs);
  }

  // ALL projections, one launch, longest-K segment first (video,image,text,audio)
  {
    const int ord[4] = {3, 1, 0, 2};   // by descending K: 2048,1024,768,512
    ProjSegs ps;
    int base = 0;
    for (int i = 0; i < 4; ++i) {
      int m = ord[i];
      int Mr = B * SL[m];
      ps.A[i] = xb[m]; ps.Bw[i] = wmb[m];
      ps.b0[i] = bm[m]; ps.b1[i] = mod_emb + m * D;
      ps.Mr[i] = Mr; ps.K[i] = DIM[m]; ps.sl[i] = SL[m]; ps.obase[i] = OFFS[m];
      base += 8 * ((Mr + 127) / 128);
      ps.blk_end[i] = base;
    }
    gemm_proj_all<<<base, 256, 0, stream>>>(ps, stacked);
  }

  // fused Q|K|V GEMM: [20336 x 3072] = stacked @ [Wq|Wk|Wv]^T
  {
    dim3 grid(24, (RROWS + 127) / 128);
    gemm_lds<0><<<grid, 256, 0, stream>>>(stacked, wqb, wkb, wvb, bq, bk, bv,
                                          qkv, RROWS, D, 3 * D);
  }

  // attention over window + mean over modalities -> fused (bf16)
  attn_fuse<<<(B * S) / 2, 256, 0, stream>>>(qkv, fusedb, bq, bk, bv, temp);

  // output GEMM: (B*S) x D, fp32 out
  {
    dim3 grid(8, (B * S) / 128);
    gemm_lds<1><<<grid, 256, 0, stream>>>(fusedb, wob, wob, wob, bo, bo, bo,
                                          d_out, B * S, D, D);
  }
}